// Round 14
// baseline (285.155 us; speedup 1.0000x reference)
//
#include <hip/hip_runtime.h>

#define D 128
#define NE 16
#define HOPS 3
#define NSUB 4      // sharded sub-lists per node (fill-side atomic depth 16 -> 4)
#define SCAP 24     // slots per sub-list (P(Poisson(4)>=24) ~ 1e-12)
#define CAP (NSUB * SCAP)
#define CPAD 32     // counter array stride per node (ints); sub-counter q at +q*8
#define LDSROW 136  // LDS row stride in bf16 elems (128 + 8 pad = 272B)

typedef __attribute__((ext_vector_type(8))) __bf16 bf16x8;
typedef __attribute__((ext_vector_type(4))) __bf16 bf16x4;
typedef __attribute__((ext_vector_type(4))) float f32x4;
typedef __attribute__((ext_vector_type(2))) float f32x2;
typedef __attribute__((ext_vector_type(4))) unsigned int u32x4;

#define PK_MASK 0x07FFFFFFu
#define PK_SHIFT 27

// ---------------- fused one-time prep (low-VGPR paths only: fill + streaming) ----------------
__global__ __launch_bounds__(256) void prep_kernel(
    const int* __restrict__ src, const int* __restrict__ dest,
    const int* __restrict__ classes, int* __restrict__ cnt,
    unsigned int* __restrict__ raw, int E, int FB,
    const float* __restrict__ Wsrc, const float* __restrict__ Wdst,
    __bf16* __restrict__ WTs, __bf16* __restrict__ WTd, int WB,
    const float* __restrict__ x, __bf16* __restrict__ xb, int n4) {
  int b = blockIdx.x;
  int tid = threadIdx.x;
  if (b < FB) {
    int e = b * 256 + tid;
    if (e < E) {
      int d = dest[e];
      int sub = e & (NSUB - 1);
      int p = atomicAdd(&cnt[(size_t)d * CPAD + sub * 8], 1);
      if (p < SCAP)
        raw[(size_t)d * CAP + sub * SCAP + p] =
            (unsigned int)src[e] | ((unsigned int)classes[e] << PK_SHIFT);
    }
  } else if (b < FB + WB) {
    int gid = (b - FB) * 256 + tid;            // < HOPS*D*D
    int h = gid >> 14;                          // D*D = 16384
    int rem = gid & 16383;
    int k = rem >> 7, nn = rem & 127;
    size_t o = (size_t)h * 16384 + nn * 128 + k;
    WTs[o] = (__bf16)Wsrc[gid];
    WTd[o] = (__bf16)Wdst[gid];
  } else {
    int i = (b - FB - WB) * 256 + tid;
    if (i < n4) {
      f32x4 v = ((const f32x4*)x)[i];
      bf16x4 o;
      o[0] = (__bf16)v[0]; o[1] = (__bf16)v[1]; o[2] = (__bf16)v[2]; o[3] = (__bf16)v[3];
      ((bf16x4*)xb)[i] = o;
    }
  }
}

// ---------------- dual GEMM, S/T split across blockIdx.y; B LDS-staged ----------------
__global__ __launch_bounds__(256) void gemm_st(const __bf16* __restrict__ xb,
    const __bf16* __restrict__ WTs, const __bf16* __restrict__ WTd,
    const float* __restrict__ bs, const float* __restrict__ bd,
    __bf16* __restrict__ s_b, __bf16* __restrict__ t_b, int n) {
  __shared__ __bf16 Bs[128 * LDSROW];   // 34.8 KB
  const __bf16* WT = blockIdx.y ? WTd : WTs;
  const float* bias = blockIdx.y ? bd : bs;
  __bf16* outb = blockIdx.y ? t_b : s_b;

  int t = threadIdx.x;
  #pragma unroll
  for (int it = 0; it < 8; ++it) {
    int idx = it * 256 + t;          // 16B chunk id; 16 chunks per row
    int row = idx >> 4;
    int c8 = idx & 15;
    bf16x8 v = *(const bf16x8*)&WT[(size_t)row * D + c8 * 8];
    *(bf16x8*)&Bs[row * LDSROW + c8 * 8] = v;
  }
  __syncthreads();

  int w = t >> 6, l = t & 63;
  int l16 = l & 15, q = l >> 4;
  bf16x8 a[2][4];
  #pragma unroll
  for (int rt = 0; rt < 2; ++rt) {
    int rowA = blockIdx.x * 128 + (w + rt * 4) * 16 + l16;
    int rsafe = rowA < n ? rowA : 0;
    #pragma unroll
    for (int ks = 0; ks < 4; ++ks)
      a[rt][ks] = *(const bf16x8*)&xb[(size_t)rsafe * D + ks * 32 + q * 8];
  }
  f32x4 acc[2][8];
  #pragma unroll
  for (int rt = 0; rt < 2; ++rt)
    #pragma unroll
    for (int n0 = 0; n0 < 8; ++n0) acc[rt][n0] = (f32x4)0.f;
  #pragma unroll
  for (int n0 = 0; n0 < 8; ++n0) {
    const __bf16* pb = &Bs[(n0 * 16 + l16) * LDSROW + q * 8];
    #pragma unroll
    for (int ks = 0; ks < 4; ++ks) {
      bf16x8 bf = *(const bf16x8*)(pb + ks * 32);
      #pragma unroll
      for (int rt = 0; rt < 2; ++rt)
        acc[rt][n0] = __builtin_amdgcn_mfma_f32_16x16x32_bf16(a[rt][ks], bf, acc[rt][n0], 0, 0, 0);
    }
  }
  #pragma unroll
  for (int rt = 0; rt < 2; ++rt) {
    int rowD = blockIdx.x * 128 + (w + rt * 4) * 16 + q * 4;
    #pragma unroll
    for (int n0 = 0; n0 < 8; ++n0) {
      int col = n0 * 16 + l16;
      float bv = bias[col];
      #pragma unroll
      for (int r = 0; r < 4; ++r) {
        int row = rowD + r;
        if (row < n) outb[(size_t)row * D + col] = (__bf16)(acc[rt][n0][r] + bv);
      }
    }
  }
}

// ---------------- compact: merge 4 sub-lists -> contiguous per-node list (once) ----------------
__global__ __launch_bounds__(256) void compact_kernel(
    const int* __restrict__ cnt, const unsigned int* __restrict__ raw,
    unsigned int* __restrict__ pk, int* __restrict__ totc, int n) {
  int wave = threadIdx.x >> 6, lane = threadIdx.x & 63;
  int node = blockIdx.x * 4 + wave;
  if (node >= n) return;
  const int* cb = &cnt[(size_t)node * CPAD];
  int c0 = min(cb[0], SCAP), c1 = min(cb[8], SCAP);
  int c2 = min(cb[16], SCAP), c3 = min(cb[24], SCAP);
  int p1 = c0, p2 = c0 + c1, p3 = p2 + c2, tot = p3 + c3;
  if (lane == 0) totc[node] = tot;
  size_t rbase = (size_t)node * CAP;
  for (int j = lane; j < tot; j += 64) {
    int s_ = (j >= p1) + (j >= p2) + (j >= p3);
    int pofs = s_ == 0 ? 0 : (s_ == 1 ? p1 : (s_ == 2 ? p2 : p3));
    pk[rbase + j] = raw[rbase + s_ * SCAP + (j - pofs)];
  }
}

// ------- fused aggregate: segment-mean(relu(s[src]+t[n]+ee[cls])) + residual + LayerNorm -------
// persistent grid-stride: each wave processes ~N/8192 nodes (load-balance averaging);
// packed f32x2 math; 4 gathers in flight per quarter; bf16 residual
__global__ __launch_bounds__(256) void aggregate_kernel(
    const __bf16* __restrict__ s_b, const __bf16* __restrict__ t_b,
    __bf16* xb,
    const int* __restrict__ totc,
    const unsigned int* __restrict__ pk,
    const float* __restrict__ ee, const float* __restrict__ gamma,
    const float* __restrict__ beta, float* __restrict__ xout,
    int last, int n) {
  __shared__ float ee_s[NE * D];
  for (int i = threadIdx.x; i < NE * D; i += 256) ee_s[i] = ee[i];
  __syncthreads();
  int wave = threadIdx.x >> 6;
  int lane = threadIdx.x & 63;
  int quarter = lane >> 4;
  int l16 = lane & 15;
  int d0 = l16 * 8;
  int wid = blockIdx.x * 4 + wave;
  int nw = gridDim.x * 4;

  for (int node = wid; node < n; node += nw) {
    size_t nbase = (size_t)node * D;
    bf16x8 tvb = *(const bf16x8*)&t_b[nbase + d0];
    f32x2 tv2[4];
    #pragma unroll
    for (int k = 0; k < 4; ++k) { tv2[k][0] = (float)tvb[2 * k]; tv2[k][1] = (float)tvb[2 * k + 1]; }
    bf16x8 xvb = *(const bf16x8*)&xb[nbase + d0];

    int tot = totc[node];
    int base = node * CAP;
    f32x2 acc2[4];
    #pragma unroll
    for (int k = 0; k < 4; ++k) acc2[k] = (f32x2)0.f;

#define EDGE_ACC(V, SU)                                                        \
    {                                                                          \
      const float* ep_ = &ee_s[((V) >> PK_SHIFT) * D + d0];                    \
      f32x4 ea_ = *(const f32x4*)ep_, eb_ = *(const f32x4*)(ep_ + 4);          \
      f32x2 epr_[4];                                                           \
      epr_[0][0] = ea_[0]; epr_[0][1] = ea_[1];                                \
      epr_[1][0] = ea_[2]; epr_[1][1] = ea_[3];                                \
      epr_[2][0] = eb_[0]; epr_[2][1] = eb_[1];                                \
      epr_[3][0] = eb_[2]; epr_[3][1] = eb_[3];                                \
      _Pragma("unroll")                                                        \
      for (int k_ = 0; k_ < 4; ++k_) {                                         \
        unsigned int u_ = (SU)[k_];                                            \
        f32x2 v_;                                                              \
        v_[0] = __uint_as_float(u_ << 16);                                     \
        v_[1] = __uint_as_float(u_ & 0xFFFF0000u);                             \
        v_ = v_ + tv2[k_] + epr_[k_];                                          \
        v_ = __builtin_elementwise_max(v_, (f32x2)0.f);                        \
        acc2[k_] += v_;                                                        \
      }                                                                        \
    }

    int j = quarter;
    for (; j + 12 < tot; j += 16) {
      unsigned int v0 = pk[base + j];
      unsigned int v1 = pk[base + j + 4];
      unsigned int v2 = pk[base + j + 8];
      unsigned int v3 = pk[base + j + 12];
      u32x4 s0 = *(const u32x4*)&s_b[(size_t)(v0 & PK_MASK) * D + d0];
      u32x4 s1 = *(const u32x4*)&s_b[(size_t)(v1 & PK_MASK) * D + d0];
      u32x4 s2 = *(const u32x4*)&s_b[(size_t)(v2 & PK_MASK) * D + d0];
      u32x4 s3 = *(const u32x4*)&s_b[(size_t)(v3 & PK_MASK) * D + d0];
      EDGE_ACC(v0, s0); EDGE_ACC(v1, s1); EDGE_ACC(v2, s2); EDGE_ACC(v3, s3);
    }
    for (; j < tot; j += 4) {
      unsigned int v0 = pk[base + j];
      u32x4 s0 = *(const u32x4*)&s_b[(size_t)(v0 & PK_MASK) * D + d0];
      EDGE_ACC(v0, s0);
    }
#undef EDGE_ACC

    // combine the 4 quarter-accumulators (lanes end with full sums)
    #pragma unroll
    for (int k = 0; k < 4; ++k) {
      acc2[k][0] += __shfl_xor(acc2[k][0], 32);
      acc2[k][0] += __shfl_xor(acc2[k][0], 16);
      acc2[k][1] += __shfl_xor(acc2[k][1], 32);
      acc2[k][1] += __shfl_xor(acc2[k][1], 16);
    }
    float invc = tot > 0 ? 1.f / (float)tot : 0.f;
    float y[8];
    #pragma unroll
    for (int k = 0; k < 4; ++k) {
      y[2 * k]     = acc2[k][0] * invc + (float)xvb[2 * k];
      y[2 * k + 1] = acc2[k][1] * invc + (float)xvb[2 * k + 1];
    }
    float ssum = 0.f;
    #pragma unroll
    for (int jj = 0; jj < 8; ++jj) ssum += y[jj];
    #pragma unroll
    for (int off = 8; off > 0; off >>= 1) ssum += __shfl_xor(ssum, off);
    float mu = ssum * (1.f / (float)D);
    float dv[8], vs = 0.f;
    #pragma unroll
    for (int jj = 0; jj < 8; ++jj) { dv[jj] = y[jj] - mu; vs += dv[jj] * dv[jj]; }
    #pragma unroll
    for (int off = 8; off > 0; off >>= 1) vs += __shfl_xor(vs, off);
    float inv = rsqrtf(vs * (1.f / (float)D) + 1e-3f);
    if (quarter == 0) {
      f32x4 g0 = *(const f32x4*)&gamma[d0];
      f32x4 g1 = *(const f32x4*)&gamma[d0 + 4];
      f32x4 b0 = *(const f32x4*)&beta[d0];
      f32x4 b1 = *(const f32x4*)&beta[d0 + 4];
      float o[8];
      #pragma unroll
      for (int jj = 0; jj < 8; ++jj)
        o[jj] = (jj < 4 ? g0[jj] : g1[jj - 4]) * dv[jj] * inv + (jj < 4 ? b0[jj] : b1[jj - 4]);
      if (last) {
        f32x4 o0, o1;
        #pragma unroll
        for (int jj = 0; jj < 4; ++jj) { o0[jj] = o[jj]; o1[jj] = o[jj + 4]; }
        *(f32x4*)&xout[nbase + d0] = o0;
        *(f32x4*)&xout[nbase + d0 + 4] = o1;
      } else {
        bf16x8 ob;
        #pragma unroll
        for (int jj = 0; jj < 8; ++jj) ob[jj] = (__bf16)o[jj];
        *(bf16x8*)&xb[nbase + d0] = ob;
      }
    }
  }
}

extern "C" void kernel_launch(void* const* d_in, const int* in_sizes, int n_in,
                              void* d_out, int out_size, void* d_ws, size_t ws_size,
                              hipStream_t stream) {
  const float* x0     = (const float*)d_in[0];
  const int*   src    = (const int*)d_in[1];
  const int*   dest   = (const int*)d_in[2];
  const int*   cls    = (const int*)d_in[3];
  const float* W_src  = (const float*)d_in[4];
  const float* b_src  = (const float*)d_in[5];
  const float* W_dest = (const float*)d_in[6];
  const float* b_dest = (const float*)d_in[7];
  const float* ee     = (const float*)d_in[8];
  const float* ln_g   = (const float*)d_in[9];
  const float* ln_b   = (const float*)d_in[10];
  float* out = (float*)d_out;

  const int N = in_sizes[0] / D;
  const int E = in_sizes[1];

  char* p = (char*)d_ws;
  __bf16* s_b = (__bf16*)p;   p += (size_t)N * D * sizeof(__bf16);
  __bf16* t_b = (__bf16*)p;   p += (size_t)N * D * sizeof(__bf16);
  __bf16* xb  = (__bf16*)p;   p += (size_t)N * D * sizeof(__bf16);
  __bf16* WTs = (__bf16*)p;   p += (size_t)HOPS * D * D * sizeof(__bf16);
  __bf16* WTd = (__bf16*)p;   p += (size_t)HOPS * D * D * sizeof(__bf16);
  int* cntb   = (int*)p;      p += (size_t)N * CPAD * sizeof(int);
  unsigned int* raw = (unsigned int*)p; p += (size_t)N * CAP * sizeof(unsigned int);
  unsigned int* pk  = (unsigned int*)p; p += (size_t)N * CAP * sizeof(unsigned int);
  int* totc   = (int*)p;      p += (size_t)N * sizeof(int);

  hipMemsetAsync(cntb, 0, (size_t)N * CPAD * sizeof(int), stream);

  const int FB = (E + 255) / 256;
  const int WB = (HOPS * D * D) / 256;
  const int n4 = N * D / 4;
  const int CB = (n4 + 255) / 256;
  prep_kernel<<<FB + WB + CB, 256, 0, stream>>>(
      src, dest, cls, cntb, raw, E, FB,
      W_src, W_dest, WTs, WTd, WB,
      x0, xb, n4);

  compact_kernel<<<(N + 3) / 4, 256, 0, stream>>>(cntb, raw, pk, totc, N);

  int aggBlocks = (N + 3) / 4;
  if (aggBlocks > 2048) aggBlocks = 2048;   // device wave capacity: 2048 x 4 waves
  for (int h = 0; h < HOPS; ++h) {
    gemm_st<<<dim3((N + 127) / 128, 2), 256, 0, stream>>>(
        xb, WTs + (size_t)h * D * D, WTd + (size_t)h * D * D,
        b_src + (size_t)h * D, b_dest + (size_t)h * D, s_b, t_b, N);
    aggregate_kernel<<<aggBlocks, 256, 0, stream>>>(
        s_b, t_b, xb, totc, pk,
        ee + (size_t)h * NE * D, ln_g + (size_t)h * D, ln_b + (size_t)h * D,
        out, (h == HOPS - 1) ? 1 : 0, N);
  }
}

// Round 15
// 276.300 us; speedup vs baseline: 1.0320x; 1.0320x over previous
//
#include <hip/hip_runtime.h>

#define D 128
#define NE 16
#define HOPS 3
#define NSUB 4      // sharded sub-lists per node (fill-side atomic depth 16 -> 4)
#define SCAP 24     // slots per sub-list (P(Poisson(4)>=24) ~ 1e-12)
#define CAP (NSUB * SCAP)
#define CPAD 32     // counter array stride per node (ints); sub-counter q at +q*8
#define LDSROW 136  // LDS row stride in bf16 elems (128 + 8 pad = 272B)

typedef __attribute__((ext_vector_type(8))) __bf16 bf16x8;
typedef __attribute__((ext_vector_type(4))) __bf16 bf16x4;
typedef __attribute__((ext_vector_type(4))) float f32x4;
typedef __attribute__((ext_vector_type(2))) float f32x2;
typedef __attribute__((ext_vector_type(4))) unsigned int u32x4;

#define PK_MASK 0x07FFFFFFu
#define PK_SHIFT 27

// ---------------- fused one-time prep (low-VGPR paths only: fill + streaming) ----------------
__global__ __launch_bounds__(256) void prep_kernel(
    const int* __restrict__ src, const int* __restrict__ dest,
    const int* __restrict__ classes, int* __restrict__ cnt,
    unsigned int* __restrict__ raw, int E, int FB,
    const float* __restrict__ Wsrc, const float* __restrict__ Wdst,
    __bf16* __restrict__ WTs, __bf16* __restrict__ WTd, int WB,
    const float* __restrict__ x, __bf16* __restrict__ xb, int n4) {
  int b = blockIdx.x;
  int tid = threadIdx.x;
  if (b < FB) {
    int e = b * 256 + tid;
    if (e < E) {
      int d = dest[e];
      int sub = e & (NSUB - 1);
      int p = atomicAdd(&cnt[(size_t)d * CPAD + sub * 8], 1);
      if (p < SCAP)
        raw[(size_t)d * CAP + sub * SCAP + p] =
            (unsigned int)src[e] | ((unsigned int)classes[e] << PK_SHIFT);
    }
  } else if (b < FB + WB) {
    int gid = (b - FB) * 256 + tid;            // < HOPS*D*D
    int h = gid >> 14;                          // D*D = 16384
    int rem = gid & 16383;
    int k = rem >> 7, nn = rem & 127;
    size_t o = (size_t)h * 16384 + nn * 128 + k;
    WTs[o] = (__bf16)Wsrc[gid];
    WTd[o] = (__bf16)Wdst[gid];
  } else {
    int i = (b - FB - WB) * 256 + tid;
    if (i < n4) {
      f32x4 v = ((const f32x4*)x)[i];
      bf16x4 o;
      o[0] = (__bf16)v[0]; o[1] = (__bf16)v[1]; o[2] = (__bf16)v[2]; o[3] = (__bf16)v[3];
      ((bf16x4*)xb)[i] = o;
    }
  }
}

// ---------------- dual GEMM, S/T split across blockIdx.y; B LDS-staged ----------------
__global__ __launch_bounds__(256) void gemm_st(const __bf16* __restrict__ xb,
    const __bf16* __restrict__ WTs, const __bf16* __restrict__ WTd,
    const float* __restrict__ bs, const float* __restrict__ bd,
    __bf16* __restrict__ s_b, __bf16* __restrict__ t_b, int n) {
  __shared__ __bf16 Bs[128 * LDSROW];   // 34.8 KB
  const __bf16* WT = blockIdx.y ? WTd : WTs;
  const float* bias = blockIdx.y ? bd : bs;
  __bf16* outb = blockIdx.y ? t_b : s_b;

  int t = threadIdx.x;
  #pragma unroll
  for (int it = 0; it < 8; ++it) {
    int idx = it * 256 + t;          // 16B chunk id; 16 chunks per row
    int row = idx >> 4;
    int c8 = idx & 15;
    bf16x8 v = *(const bf16x8*)&WT[(size_t)row * D + c8 * 8];
    *(bf16x8*)&Bs[row * LDSROW + c8 * 8] = v;
  }
  __syncthreads();

  int w = t >> 6, l = t & 63;
  int l16 = l & 15, q = l >> 4;
  bf16x8 a[2][4];
  #pragma unroll
  for (int rt = 0; rt < 2; ++rt) {
    int rowA = blockIdx.x * 128 + (w + rt * 4) * 16 + l16;
    int rsafe = rowA < n ? rowA : 0;
    #pragma unroll
    for (int ks = 0; ks < 4; ++ks)
      a[rt][ks] = *(const bf16x8*)&xb[(size_t)rsafe * D + ks * 32 + q * 8];
  }
  f32x4 acc[2][8];
  #pragma unroll
  for (int rt = 0; rt < 2; ++rt)
    #pragma unroll
    for (int n0 = 0; n0 < 8; ++n0) acc[rt][n0] = (f32x4)0.f;
  #pragma unroll
  for (int n0 = 0; n0 < 8; ++n0) {
    const __bf16* pb = &Bs[(n0 * 16 + l16) * LDSROW + q * 8];
    #pragma unroll
    for (int ks = 0; ks < 4; ++ks) {
      bf16x8 bf = *(const bf16x8*)(pb + ks * 32);
      #pragma unroll
      for (int rt = 0; rt < 2; ++rt)
        acc[rt][n0] = __builtin_amdgcn_mfma_f32_16x16x32_bf16(a[rt][ks], bf, acc[rt][n0], 0, 0, 0);
    }
  }
  #pragma unroll
  for (int rt = 0; rt < 2; ++rt) {
    int rowD = blockIdx.x * 128 + (w + rt * 4) * 16 + q * 4;
    #pragma unroll
    for (int n0 = 0; n0 < 8; ++n0) {
      int col = n0 * 16 + l16;
      float bv = bias[col];
      #pragma unroll
      for (int r = 0; r < 4; ++r) {
        int row = rowD + r;
        if (row < n) outb[(size_t)row * D + col] = (__bf16)(acc[rt][n0][r] + bv);
      }
    }
  }
}

// ---------------- compact: merge sub-lists -> per-node QUARTER-PARTITIONED list (once) ----------------
// logical concat index j -> pk[node*CAP + (j&3)*SCAP + (j>>2)]
// (quarter q of the aggregate wave reads its edges contiguously at base + q*SCAP)
__global__ __launch_bounds__(256) void compact_kernel(
    const int* __restrict__ cnt, const unsigned int* __restrict__ raw,
    unsigned int* __restrict__ pk, int* __restrict__ totc, int n) {
  int wave = threadIdx.x >> 6, lane = threadIdx.x & 63;
  int node = blockIdx.x * 4 + wave;
  if (node >= n) return;
  const int* cb = &cnt[(size_t)node * CPAD];
  int c0 = min(cb[0], SCAP), c1 = min(cb[8], SCAP);
  int c2 = min(cb[16], SCAP), c3 = min(cb[24], SCAP);
  int p1 = c0, p2 = c0 + c1, p3 = p2 + c2, tot = p3 + c3;
  if (lane == 0) totc[node] = tot;
  size_t rbase = (size_t)node * CAP;
  for (int j = lane; j < tot; j += 64) {
    int s_ = (j >= p1) + (j >= p2) + (j >= p3);
    int pofs = s_ == 0 ? 0 : (s_ == 1 ? p1 : (s_ == 2 ? p2 : p3));
    pk[rbase + (j & 3) * SCAP + (j >> 2)] = raw[rbase + s_ * SCAP + (j - pofs)];
  }
}

// ------- fused aggregate: segment-mean(relu(s[src]+t[n]+ee[cls])) + residual + LayerNorm -------
// one wave per node (R13 structure); quarter q reads contiguous index block -> ONE u32x4
// index load per 4-gather batch; packed f32x2 math; bf16 residual
__global__ __launch_bounds__(256) void aggregate_kernel(
    const __bf16* __restrict__ s_b, const __bf16* __restrict__ t_b,
    __bf16* xb,
    const int* __restrict__ totc,
    const unsigned int* __restrict__ pk,
    const float* __restrict__ ee, const float* __restrict__ gamma,
    const float* __restrict__ beta, float* __restrict__ xout,
    int last, int n) {
  __shared__ float ee_s[NE * D];
  for (int i = threadIdx.x; i < NE * D; i += 256) ee_s[i] = ee[i];
  __syncthreads();
  int wave = threadIdx.x >> 6;
  int lane = threadIdx.x & 63;
  int node = blockIdx.x * 4 + wave;
  if (node >= n) return;
  int quarter = lane >> 4;
  int l16 = lane & 15;
  int d0 = l16 * 8;
  size_t nbase = (size_t)node * D;
  bf16x8 tvb = *(const bf16x8*)&t_b[nbase + d0];
  f32x2 tv2[4];
  #pragma unroll
  for (int k = 0; k < 4; ++k) { tv2[k][0] = (float)tvb[2 * k]; tv2[k][1] = (float)tvb[2 * k + 1]; }
  bf16x8 xvb = *(const bf16x8*)&xb[nbase + d0];

  int tot = totc[node];
  int cq = (tot - quarter + 3) >> 2;          // edges owned by this quarter
  int qbase = node * CAP + quarter * SCAP;    // contiguous per-quarter block
  f32x2 acc2[4];
  #pragma unroll
  for (int k = 0; k < 4; ++k) acc2[k] = (f32x2)0.f;

#define EDGE_ACC(V, SU)                                                        \
  {                                                                            \
    const float* ep_ = &ee_s[((V) >> PK_SHIFT) * D + d0];                      \
    f32x4 ea_ = *(const f32x4*)ep_, eb_ = *(const f32x4*)(ep_ + 4);            \
    f32x2 epr_[4];                                                             \
    epr_[0][0] = ea_[0]; epr_[0][1] = ea_[1];                                  \
    epr_[1][0] = ea_[2]; epr_[1][1] = ea_[3];                                  \
    epr_[2][0] = eb_[0]; epr_[2][1] = eb_[1];                                  \
    epr_[3][0] = eb_[2]; epr_[3][1] = eb_[3];                                  \
    _Pragma("unroll")                                                          \
    for (int k_ = 0; k_ < 4; ++k_) {                                           \
      unsigned int u_ = (SU)[k_];                                              \
      f32x2 v_;                                                                \
      v_[0] = __uint_as_float(u_ << 16);                                       \
      v_[1] = __uint_as_float(u_ & 0xFFFF0000u);                               \
      v_ = v_ + tv2[k_] + epr_[k_];                                            \
      v_ = __builtin_elementwise_max(v_, (f32x2)0.f);                          \
      acc2[k_] += v_;                                                          \
    }                                                                          \
  }

  int i = 0;
  for (; i + 3 < cq; i += 4) {
    u32x4 vi = *(const u32x4*)&pk[qbase + i];   // 4 indices in ONE load (16B-aligned)
    u32x4 s0 = *(const u32x4*)&s_b[(size_t)(vi[0] & PK_MASK) * D + d0];
    u32x4 s1 = *(const u32x4*)&s_b[(size_t)(vi[1] & PK_MASK) * D + d0];
    u32x4 s2 = *(const u32x4*)&s_b[(size_t)(vi[2] & PK_MASK) * D + d0];
    u32x4 s3 = *(const u32x4*)&s_b[(size_t)(vi[3] & PK_MASK) * D + d0];
    EDGE_ACC(vi[0], s0); EDGE_ACC(vi[1], s1); EDGE_ACC(vi[2], s2); EDGE_ACC(vi[3], s3);
  }
  if (i + 1 < cq) {
    unsigned int v0 = pk[qbase + i];
    unsigned int v1 = pk[qbase + i + 1];
    u32x4 s0 = *(const u32x4*)&s_b[(size_t)(v0 & PK_MASK) * D + d0];
    u32x4 s1 = *(const u32x4*)&s_b[(size_t)(v1 & PK_MASK) * D + d0];
    EDGE_ACC(v0, s0); EDGE_ACC(v1, s1);
    i += 2;
  }
  if (i < cq) {
    unsigned int v0 = pk[qbase + i];
    u32x4 s0 = *(const u32x4*)&s_b[(size_t)(v0 & PK_MASK) * D + d0];
    EDGE_ACC(v0, s0);
  }
#undef EDGE_ACC

  // combine the 4 quarter-accumulators (lanes end with full sums)
  #pragma unroll
  for (int k = 0; k < 4; ++k) {
    acc2[k][0] += __shfl_xor(acc2[k][0], 32);
    acc2[k][0] += __shfl_xor(acc2[k][0], 16);
    acc2[k][1] += __shfl_xor(acc2[k][1], 32);
    acc2[k][1] += __shfl_xor(acc2[k][1], 16);
  }
  float invc = tot > 0 ? 1.f / (float)tot : 0.f;
  float y[8];
  #pragma unroll
  for (int k = 0; k < 4; ++k) {
    y[2 * k]     = acc2[k][0] * invc + (float)xvb[2 * k];
    y[2 * k + 1] = acc2[k][1] * invc + (float)xvb[2 * k + 1];
  }
  float ssum = 0.f;
  #pragma unroll
  for (int jj = 0; jj < 8; ++jj) ssum += y[jj];
  #pragma unroll
  for (int off = 8; off > 0; off >>= 1) ssum += __shfl_xor(ssum, off);
  float mu = ssum * (1.f / (float)D);
  float dv[8], vs = 0.f;
  #pragma unroll
  for (int jj = 0; jj < 8; ++jj) { dv[jj] = y[jj] - mu; vs += dv[jj] * dv[jj]; }
  #pragma unroll
  for (int off = 8; off > 0; off >>= 1) vs += __shfl_xor(vs, off);
  float inv = rsqrtf(vs * (1.f / (float)D) + 1e-3f);
  if (quarter == 0) {
    f32x4 g0 = *(const f32x4*)&gamma[d0];
    f32x4 g1 = *(const f32x4*)&gamma[d0 + 4];
    f32x4 b0 = *(const f32x4*)&beta[d0];
    f32x4 b1 = *(const f32x4*)&beta[d0 + 4];
    float o[8];
    #pragma unroll
    for (int jj = 0; jj < 8; ++jj)
      o[jj] = (jj < 4 ? g0[jj] : g1[jj - 4]) * dv[jj] * inv + (jj < 4 ? b0[jj] : b1[jj - 4]);
    if (last) {
      f32x4 o0, o1;
      #pragma unroll
      for (int jj = 0; jj < 4; ++jj) { o0[jj] = o[jj]; o1[jj] = o[jj + 4]; }
      *(f32x4*)&xout[nbase + d0] = o0;
      *(f32x4*)&xout[nbase + d0 + 4] = o1;
    } else {
      bf16x8 ob;
      #pragma unroll
      for (int jj = 0; jj < 8; ++jj) ob[jj] = (__bf16)o[jj];
      *(bf16x8*)&xb[nbase + d0] = ob;
    }
  }
}

extern "C" void kernel_launch(void* const* d_in, const int* in_sizes, int n_in,
                              void* d_out, int out_size, void* d_ws, size_t ws_size,
                              hipStream_t stream) {
  const float* x0     = (const float*)d_in[0];
  const int*   src    = (const int*)d_in[1];
  const int*   dest   = (const int*)d_in[2];
  const int*   cls    = (const int*)d_in[3];
  const float* W_src  = (const float*)d_in[4];
  const float* b_src  = (const float*)d_in[5];
  const float* W_dest = (const float*)d_in[6];
  const float* b_dest = (const float*)d_in[7];
  const float* ee     = (const float*)d_in[8];
  const float* ln_g   = (const float*)d_in[9];
  const float* ln_b   = (const float*)d_in[10];
  float* out = (float*)d_out;

  const int N = in_sizes[0] / D;
  const int E = in_sizes[1];

  char* p = (char*)d_ws;
  __bf16* s_b = (__bf16*)p;   p += (size_t)N * D * sizeof(__bf16);
  __bf16* t_b = (__bf16*)p;   p += (size_t)N * D * sizeof(__bf16);
  __bf16* xb  = (__bf16*)p;   p += (size_t)N * D * sizeof(__bf16);
  __bf16* WTs = (__bf16*)p;   p += (size_t)HOPS * D * D * sizeof(__bf16);
  __bf16* WTd = (__bf16*)p;   p += (size_t)HOPS * D * D * sizeof(__bf16);
  int* cntb   = (int*)p;      p += (size_t)N * CPAD * sizeof(int);
  unsigned int* raw = (unsigned int*)p; p += (size_t)N * CAP * sizeof(unsigned int);
  unsigned int* pk  = (unsigned int*)p; p += (size_t)N * CAP * sizeof(unsigned int);
  int* totc   = (int*)p;      p += (size_t)N * sizeof(int);

  hipMemsetAsync(cntb, 0, (size_t)N * CPAD * sizeof(int), stream);

  const int FB = (E + 255) / 256;
  const int WB = (HOPS * D * D) / 256;
  const int n4 = N * D / 4;
  const int CB = (n4 + 255) / 256;
  prep_kernel<<<FB + WB + CB, 256, 0, stream>>>(
      src, dest, cls, cntb, raw, E, FB,
      W_src, W_dest, WTs, WTd, WB,
      x0, xb, n4);

  compact_kernel<<<(N + 3) / 4, 256, 0, stream>>>(cntb, raw, pk, totc, N);

  for (int h = 0; h < HOPS; ++h) {
    gemm_st<<<dim3((N + 127) / 128, 2), 256, 0, stream>>>(
        xb, WTs + (size_t)h * D * D, WTd + (size_t)h * D * D,
        b_src + (size_t)h * D, b_dest + (size_t)h * D, s_b, t_b, N);
    aggregate_kernel<<<(N + 3) / 4, 256, 0, stream>>>(
        s_b, t_b, xb, totc, pk,
        ee + (size_t)h * NE * D, ln_g + (size_t)h * D, ln_b + (size_t)h * D,
        out, (h == HOPS - 1) ? 1 : 0, N);
  }
}

// Round 16
// 263.005 us; speedup vs baseline: 1.0842x; 1.0506x over previous
//
#include <hip/hip_runtime.h>

#define D 128
#define NE 16
#define HOPS 3
#define NSUB 4      // sharded sub-lists per node (fill-side atomic depth 16 -> 4)
#define SCAP 24     // slots per sub-list (P(Poisson(4)>=24) ~ 1e-12)
#define CAP (NSUB * SCAP)
#define CPAD 32     // counter array stride per node (ints); sub-counter q at +q*8
#define LDSROW 136  // LDS row stride in bf16 elems (128 + 8 pad = 272B)

typedef __attribute__((ext_vector_type(8))) __bf16 bf16x8;
typedef __attribute__((ext_vector_type(4))) __bf16 bf16x4;
typedef __attribute__((ext_vector_type(4))) float f32x4;
typedef __attribute__((ext_vector_type(2))) float f32x2;
typedef __attribute__((ext_vector_type(4))) unsigned int u32x4;

#define PK_MASK 0x07FFFFFFu
#define PK_SHIFT 27

// ---------------- fused one-time prep (low-VGPR paths only: fill + streaming) ----------------
__global__ __launch_bounds__(256) void prep_kernel(
    const int* __restrict__ src, const int* __restrict__ dest,
    const int* __restrict__ classes, int* __restrict__ cnt,
    unsigned int* __restrict__ raw, int E, int FB,
    const float* __restrict__ Wsrc, const float* __restrict__ Wdst,
    __bf16* __restrict__ WTs, __bf16* __restrict__ WTd, int WB,
    const float* __restrict__ x, __bf16* __restrict__ xb, int n4) {
  int b = blockIdx.x;
  int tid = threadIdx.x;
  if (b < FB) {
    int e = b * 256 + tid;
    if (e < E) {
      int d = dest[e];
      int sub = e & (NSUB - 1);
      int p = atomicAdd(&cnt[(size_t)d * CPAD + sub * 8], 1);
      if (p < SCAP)
        raw[(size_t)d * CAP + sub * SCAP + p] =
            (unsigned int)src[e] | ((unsigned int)classes[e] << PK_SHIFT);
    }
  } else if (b < FB + WB) {
    int gid = (b - FB) * 256 + tid;            // < HOPS*D*D
    int h = gid >> 14;                          // D*D = 16384
    int rem = gid & 16383;
    int k = rem >> 7, nn = rem & 127;
    size_t o = (size_t)h * 16384 + nn * 128 + k;
    WTs[o] = (__bf16)Wsrc[gid];
    WTd[o] = (__bf16)Wdst[gid];
  } else {
    int i = (b - FB - WB) * 256 + tid;
    if (i < n4) {
      f32x4 v = ((const f32x4*)x)[i];
      bf16x4 o;
      o[0] = (__bf16)v[0]; o[1] = (__bf16)v[1]; o[2] = (__bf16)v[2]; o[3] = (__bf16)v[3];
      ((bf16x4*)xb)[i] = o;
    }
  }
}

// ---------------- dual GEMM, S/T split across blockIdx.y; B LDS-staged ----------------
__global__ __launch_bounds__(256) void gemm_st(const __bf16* __restrict__ xb,
    const __bf16* __restrict__ WTs, const __bf16* __restrict__ WTd,
    const float* __restrict__ bs, const float* __restrict__ bd,
    __bf16* __restrict__ s_b, __bf16* __restrict__ t_b, int n) {
  __shared__ __bf16 Bs[128 * LDSROW];   // 34.8 KB
  const __bf16* WT = blockIdx.y ? WTd : WTs;
  const float* bias = blockIdx.y ? bd : bs;
  __bf16* outb = blockIdx.y ? t_b : s_b;

  int t = threadIdx.x;
  #pragma unroll
  for (int it = 0; it < 8; ++it) {
    int idx = it * 256 + t;          // 16B chunk id; 16 chunks per row
    int row = idx >> 4;
    int c8 = idx & 15;
    bf16x8 v = *(const bf16x8*)&WT[(size_t)row * D + c8 * 8];
    *(bf16x8*)&Bs[row * LDSROW + c8 * 8] = v;
  }
  __syncthreads();

  int w = t >> 6, l = t & 63;
  int l16 = l & 15, q = l >> 4;
  bf16x8 a[2][4];
  #pragma unroll
  for (int rt = 0; rt < 2; ++rt) {
    int rowA = blockIdx.x * 128 + (w + rt * 4) * 16 + l16;
    int rsafe = rowA < n ? rowA : 0;
    #pragma unroll
    for (int ks = 0; ks < 4; ++ks)
      a[rt][ks] = *(const bf16x8*)&xb[(size_t)rsafe * D + ks * 32 + q * 8];
  }
  f32x4 acc[2][8];
  #pragma unroll
  for (int rt = 0; rt < 2; ++rt)
    #pragma unroll
    for (int n0 = 0; n0 < 8; ++n0) acc[rt][n0] = (f32x4)0.f;
  #pragma unroll
  for (int n0 = 0; n0 < 8; ++n0) {
    const __bf16* pb = &Bs[(n0 * 16 + l16) * LDSROW + q * 8];
    #pragma unroll
    for (int ks = 0; ks < 4; ++ks) {
      bf16x8 bf = *(const bf16x8*)(pb + ks * 32);
      #pragma unroll
      for (int rt = 0; rt < 2; ++rt)
        acc[rt][n0] = __builtin_amdgcn_mfma_f32_16x16x32_bf16(a[rt][ks], bf, acc[rt][n0], 0, 0, 0);
    }
  }
  #pragma unroll
  for (int rt = 0; rt < 2; ++rt) {
    int rowD = blockIdx.x * 128 + (w + rt * 4) * 16 + q * 4;
    #pragma unroll
    for (int n0 = 0; n0 < 8; ++n0) {
      int col = n0 * 16 + l16;
      float bv = bias[col];
      #pragma unroll
      for (int r = 0; r < 4; ++r) {
        int row = rowD + r;
        if (row < n) outb[(size_t)row * D + col] = (__bf16)(acc[rt][n0][r] + bv);
      }
    }
  }
}

// ---------------- compact: merge 4 sub-lists -> contiguous per-node list (once) ----------------
__global__ __launch_bounds__(256) void compact_kernel(
    const int* __restrict__ cnt, const unsigned int* __restrict__ raw,
    unsigned int* __restrict__ pk, int* __restrict__ totc, int n) {
  int wave = threadIdx.x >> 6, lane = threadIdx.x & 63;
  int node = blockIdx.x * 4 + wave;
  if (node >= n) return;
  const int* cb = &cnt[(size_t)node * CPAD];
  int c0 = min(cb[0], SCAP), c1 = min(cb[8], SCAP);
  int c2 = min(cb[16], SCAP), c3 = min(cb[24], SCAP);
  int p1 = c0, p2 = c0 + c1, p3 = p2 + c2, tot = p3 + c3;
  if (lane == 0) totc[node] = tot;
  size_t rbase = (size_t)node * CAP;
  for (int j = lane; j < tot; j += 64) {
    int s_ = (j >= p1) + (j >= p2) + (j >= p3);
    int pofs = s_ == 0 ? 0 : (s_ == 1 ? p1 : (s_ == 2 ? p2 : p3));
    pk[rbase + j] = raw[rbase + s_ * SCAP + (j - pofs)];
  }
}

// ------- fused aggregate: segment-mean(relu(s[src]+t[n]+ee[cls])) + residual + LayerNorm -------
// one wave per node; packed f32x2 math; 4 gathers in flight per quarter; bf16 residual
// last==0: write only bf16 xb (next hop input).  last==1: write only fp32 xout.
__global__ __launch_bounds__(256) void aggregate_kernel(
    const __bf16* __restrict__ s_b, const __bf16* __restrict__ t_b,
    __bf16* xb,
    const int* __restrict__ totc,
    const unsigned int* __restrict__ pk,
    const float* __restrict__ ee, const float* __restrict__ gamma,
    const float* __restrict__ beta, float* __restrict__ xout,
    int last, int n) {
  __shared__ float ee_s[NE * D];
  for (int i = threadIdx.x; i < NE * D; i += 256) ee_s[i] = ee[i];
  __syncthreads();
  int wave = threadIdx.x >> 6;
  int lane = threadIdx.x & 63;
  int node = blockIdx.x * 4 + wave;
  if (node >= n) return;
  int quarter = lane >> 4;
  int l16 = lane & 15;
  int d0 = l16 * 8;
  size_t nbase = (size_t)node * D;
  bf16x8 tvb = *(const bf16x8*)&t_b[nbase + d0];
  f32x2 tv2[4];
  #pragma unroll
  for (int k = 0; k < 4; ++k) { tv2[k][0] = (float)tvb[2 * k]; tv2[k][1] = (float)tvb[2 * k + 1]; }
  bf16x8 xvb = *(const bf16x8*)&xb[nbase + d0];

  int tot = totc[node];
  int base = node * CAP;
  f32x2 acc2[4];
  #pragma unroll
  for (int k = 0; k < 4; ++k) acc2[k] = (f32x2)0.f;

#define EDGE_ACC(V, SU)                                                        \
  {                                                                            \
    const float* ep_ = &ee_s[((V) >> PK_SHIFT) * D + d0];                      \
    f32x4 ea_ = *(const f32x4*)ep_, eb_ = *(const f32x4*)(ep_ + 4);            \
    f32x2 epr_[4];                                                             \
    epr_[0][0] = ea_[0]; epr_[0][1] = ea_[1];                                  \
    epr_[1][0] = ea_[2]; epr_[1][1] = ea_[3];                                  \
    epr_[2][0] = eb_[0]; epr_[2][1] = eb_[1];                                  \
    epr_[3][0] = eb_[2]; epr_[3][1] = eb_[3];                                  \
    _Pragma("unroll")                                                          \
    for (int k_ = 0; k_ < 4; ++k_) {                                           \
      unsigned int u_ = (SU)[k_];                                              \
      f32x2 v_;                                                                \
      v_[0] = __uint_as_float(u_ << 16);                                       \
      v_[1] = __uint_as_float(u_ & 0xFFFF0000u);                               \
      v_ = v_ + tv2[k_] + epr_[k_];                                            \
      v_ = __builtin_elementwise_max(v_, (f32x2)0.f);                          \
      acc2[k_] += v_;                                                          \
    }                                                                          \
  }

  int j = quarter;
  for (; j + 12 < tot; j += 16) {
    unsigned int v0 = pk[base + j];
    unsigned int v1 = pk[base + j + 4];
    unsigned int v2 = pk[base + j + 8];
    unsigned int v3 = pk[base + j + 12];
    u32x4 s0 = *(const u32x4*)&s_b[(size_t)(v0 & PK_MASK) * D + d0];
    u32x4 s1 = *(const u32x4*)&s_b[(size_t)(v1 & PK_MASK) * D + d0];
    u32x4 s2 = *(const u32x4*)&s_b[(size_t)(v2 & PK_MASK) * D + d0];
    u32x4 s3 = *(const u32x4*)&s_b[(size_t)(v3 & PK_MASK) * D + d0];
    EDGE_ACC(v0, s0); EDGE_ACC(v1, s1); EDGE_ACC(v2, s2); EDGE_ACC(v3, s3);
  }
  for (; j < tot; j += 4) {
    unsigned int v0 = pk[base + j];
    u32x4 s0 = *(const u32x4*)&s_b[(size_t)(v0 & PK_MASK) * D + d0];
    EDGE_ACC(v0, s0);
  }
#undef EDGE_ACC

  // combine the 4 quarter-accumulators (lanes end with full sums)
  #pragma unroll
  for (int k = 0; k < 4; ++k) {
    acc2[k][0] += __shfl_xor(acc2[k][0], 32);
    acc2[k][0] += __shfl_xor(acc2[k][0], 16);
    acc2[k][1] += __shfl_xor(acc2[k][1], 32);
    acc2[k][1] += __shfl_xor(acc2[k][1], 16);
  }
  float invc = tot > 0 ? 1.f / (float)tot : 0.f;
  float y[8];
  #pragma unroll
  for (int k = 0; k < 4; ++k) {
    y[2 * k]     = acc2[k][0] * invc + (float)xvb[2 * k];
    y[2 * k + 1] = acc2[k][1] * invc + (float)xvb[2 * k + 1];
  }
  float ssum = 0.f;
  #pragma unroll
  for (int jj = 0; jj < 8; ++jj) ssum += y[jj];
  #pragma unroll
  for (int off = 8; off > 0; off >>= 1) ssum += __shfl_xor(ssum, off);
  float mu = ssum * (1.f / (float)D);
  float dv[8], vs = 0.f;
  #pragma unroll
  for (int jj = 0; jj < 8; ++jj) { dv[jj] = y[jj] - mu; vs += dv[jj] * dv[jj]; }
  #pragma unroll
  for (int off = 8; off > 0; off >>= 1) vs += __shfl_xor(vs, off);
  float inv = rsqrtf(vs * (1.f / (float)D) + 1e-3f);
  if (quarter == 0) {
    f32x4 g0 = *(const f32x4*)&gamma[d0];
    f32x4 g1 = *(const f32x4*)&gamma[d0 + 4];
    f32x4 b0 = *(const f32x4*)&beta[d0];
    f32x4 b1 = *(const f32x4*)&beta[d0 + 4];
    float o[8];
    #pragma unroll
    for (int jj = 0; jj < 8; ++jj)
      o[jj] = (jj < 4 ? g0[jj] : g1[jj - 4]) * dv[jj] * inv + (jj < 4 ? b0[jj] : b1[jj - 4]);
    if (last) {
      f32x4 o0, o1;
      #pragma unroll
      for (int jj = 0; jj < 4; ++jj) { o0[jj] = o[jj]; o1[jj] = o[jj + 4]; }
      *(f32x4*)&xout[nbase + d0] = o0;
      *(f32x4*)&xout[nbase + d0 + 4] = o1;
    } else {
      bf16x8 ob;
      #pragma unroll
      for (int jj = 0; jj < 8; ++jj) ob[jj] = (__bf16)o[jj];
      *(bf16x8*)&xb[nbase + d0] = ob;
    }
  }
}

extern "C" void kernel_launch(void* const* d_in, const int* in_sizes, int n_in,
                              void* d_out, int out_size, void* d_ws, size_t ws_size,
                              hipStream_t stream) {
  const float* x0     = (const float*)d_in[0];
  const int*   src    = (const int*)d_in[1];
  const int*   dest   = (const int*)d_in[2];
  const int*   cls    = (const int*)d_in[3];
  const float* W_src  = (const float*)d_in[4];
  const float* b_src  = (const float*)d_in[5];
  const float* W_dest = (const float*)d_in[6];
  const float* b_dest = (const float*)d_in[7];
  const float* ee     = (const float*)d_in[8];
  const float* ln_g   = (const float*)d_in[9];
  const float* ln_b   = (const float*)d_in[10];
  float* out = (float*)d_out;

  const int N = in_sizes[0] / D;
  const int E = in_sizes[1];

  char* p = (char*)d_ws;
  __bf16* s_b = (__bf16*)p;   p += (size_t)N * D * sizeof(__bf16);
  __bf16* t_b = (__bf16*)p;   p += (size_t)N * D * sizeof(__bf16);
  __bf16* xb  = (__bf16*)p;   p += (size_t)N * D * sizeof(__bf16);
  __bf16* WTs = (__bf16*)p;   p += (size_t)HOPS * D * D * sizeof(__bf16);
  __bf16* WTd = (__bf16*)p;   p += (size_t)HOPS * D * D * sizeof(__bf16);
  int* cntb   = (int*)p;      p += (size_t)N * CPAD * sizeof(int);
  unsigned int* raw = (unsigned int*)p; p += (size_t)N * CAP * sizeof(unsigned int);
  unsigned int* pk  = (unsigned int*)p; p += (size_t)N * CAP * sizeof(unsigned int);
  int* totc   = (int*)p;      p += (size_t)N * sizeof(int);

  hipMemsetAsync(cntb, 0, (size_t)N * CPAD * sizeof(int), stream);

  const int FB = (E + 255) / 256;
  const int WB = (HOPS * D * D) / 256;
  const int n4 = N * D / 4;
  const int CB = (n4 + 255) / 256;
  prep_kernel<<<FB + WB + CB, 256, 0, stream>>>(
      src, dest, cls, cntb, raw, E, FB,
      W_src, W_dest, WTs, WTd, WB,
      x0, xb, n4);

  compact_kernel<<<(N + 3) / 4, 256, 0, stream>>>(cntb, raw, pk, totc, N);

  for (int h = 0; h < HOPS; ++h) {
    gemm_st<<<dim3((N + 127) / 128, 2), 256, 0, stream>>>(
        xb, WTs + (size_t)h * D * D, WTd + (size_t)h * D * D,
        b_src + (size_t)h * D, b_dest + (size_t)h * D, s_b, t_b, N);
    aggregate_kernel<<<(N + 3) / 4, 256, 0, stream>>>(
        s_b, t_b, xb, totc, pk,
        ee + (size_t)h * NE * D, ln_g + (size_t)h * D, ln_b + (size_t)h * D,
        out, (h == HOPS - 1) ? 1 : 0, N);
  }
}